// Round 5
// baseline (309.143 us; speedup 1.0000x reference)
//
#include <hip/hip_runtime.h>

#define H    128
#define NB   4
#define NR   8
#define DT   32    // dst-nodes per block in fused kernel

typedef __attribute__((ext_vector_type(8))) short short8;
typedef __attribute__((ext_vector_type(4))) float f32x4;

static __device__ __forceinline__ unsigned short f2bf(float f) {
    unsigned u = __float_as_uint(f);
    unsigned r = (u + 0x7fffu + ((u >> 16) & 1u)) >> 16;
    return (unsigned short)r;
}
static __device__ __forceinline__ float bf_lo(unsigned v) {
    return __uint_as_float((v & 0xffffu) << 16);
}
static __device__ __forceinline__ float bf_hi(unsigned v) {
    return __uint_as_float(v & 0xffff0000u);
}

// ---------------- zero int array ----------------
__global__ __launch_bounds__(256) void zero_i(int* __restrict__ p, int n) {
    int i = blockIdx.x * 256 + threadIdx.x;
    if (i < n) p[i] = 0;
}

// ---------------- degree histogram (dst only) ----------------
__global__ __launch_bounds__(256) void hist_dst(const int* __restrict__ dst,
                                                int* __restrict__ counts, int E) {
    int e = blockIdx.x * 256 + threadIdx.x;
    if (e < E) atomicAdd(&counts[dst[e]], 1);
}

// ---------------- hierarchical scan stage 1 ----------------
__global__ __launch_bounds__(1024) void scan_blocks(const int* __restrict__ counts,
                                                    int* __restrict__ partial,
                                                    int* __restrict__ blocksums, int n) {
    __shared__ int buf[1024];
    int tid = threadIdx.x;
    int i = blockIdx.x * 1024 + tid;
    buf[tid] = (i < n) ? counts[i] : 0;
    __syncthreads();
#pragma unroll
    for (int off = 1; off < 1024; off <<= 1) {
        int t = (tid >= off) ? buf[tid - off] : 0;
        __syncthreads();
        buf[tid] += t;
        __syncthreads();
    }
    if (i < n) partial[i] = buf[tid];
    if (tid == 1023) blocksums[blockIdx.x] = buf[1023];
}

// ---------------- stage 2: single-wave scan of block sums (nb <= 64) ----------------
__global__ __launch_bounds__(64) void scan_carry(int* __restrict__ blocksums, int nb) {
    int tid = threadIdx.x;
    int v = (tid < nb) ? blocksums[tid] : 0;
#pragma unroll
    for (int off = 1; off < 64; off <<= 1) {
        int t = __shfl_up(v, off);
        if (tid >= off) v += t;
    }
    if (tid < nb) blocksums[tid] = v;
}

// ---------------- stage 3: add carry, emit offs[0..n] ----------------
__global__ __launch_bounds__(256) void scan_add(const int* __restrict__ partial,
                                                const int* __restrict__ blocksums,
                                                int* __restrict__ offs, int n) {
    int i = blockIdx.x * 256 + threadIdx.x;
    if (i >= n) return;
    int b = i >> 10;
    int carry = (b > 0) ? blocksums[b - 1] : 0;
    offs[i + 1] = partial[i] + carry;
    if (i == 0) offs[0] = 0;
}

// ------- scatter edges into CSR (by dst); fold comp into per-edge weights -------
__global__ __launch_bounds__(256) void scatter_edges(
        const int* __restrict__ src, const int* __restrict__ dst,
        const int* __restrict__ etype, const float* __restrict__ norm,
        const float* __restrict__ comp,
        const int* __restrict__ offs, int* __restrict__ counts,
        int* __restrict__ ridx, float4* __restrict__ cw, int E) {
    int e = blockIdx.x * 256 + threadIdx.x;
    if (e >= E) return;
    int d = dst[e];
    int pos = offs[d] + atomicSub(&counts[d], 1) - 1;
    ridx[pos] = src[e];
    float w = norm[e];
    float4 c = *(const float4*)(comp + etype[e] * NB);
    cw[pos] = make_float4(w * c.x, w * c.y, w * c.z, w * c.w);
}

// ---------------- f32 -> bf16 convert ----------------
__global__ __launch_bounds__(256) void convert_bf16(const float* __restrict__ in,
                                                    unsigned short* __restrict__ out, int n4) {
    int i = blockIdx.x * 256 + threadIdx.x;
    if (i >= n4) return;
    float4 v = ((const float4*)in)[i];
    ushort4 o;
    o.x = f2bf(v.x); o.y = f2bf(v.y); o.z = f2bf(v.z); o.w = f2bf(v.w);
    ((ushort4*)out)[i] = o;
}

// ---- Wb build: Wb[l][o][b*128+d] = bf16(basis_l[b][d][o])  (pure transpose) ----
__global__ __launch_bounds__(128) void make_wb(
        const float* __restrict__ basis0, const float* __restrict__ basis1,
        unsigned short* __restrict__ Wb) {
    int b = blockIdx.x;        // 0..3
    int d = blockIdx.y;        // 0..127
    int l = blockIdx.z;        // 0..1
    int o = threadIdx.x;       // 0..127
    const float* basis = l ? basis1 : basis0;
    float s = basis[((size_t)b * H + d) * H + o];
    Wb[((size_t)l * H + o) * (NB * H) + b * H + d] = f2bf(s);
}

// ---------------- fused layer: basis-agg (LDS) + MFMA GEMM + bias + relu ----------------
// block = 512 threads (8 waves), DT=32 dst nodes, K = NB*H = 512.
// Phase A: wave w aggregates nodes w*4..w*4+3 into AggTile[32][512] bf16 (swizzled).
// Phase B: wave w computes output cols [w*16, w*16+16) for all 32 rows.
__global__ __launch_bounds__(512) void fused_layer(
        const unsigned short* __restrict__ hin,   // [M][128] bf16
        const int* __restrict__ offs,             // [M+1]
        const int* __restrict__ ridx,             // src per edge, CSR by dst
        const float4* __restrict__ cw,            // norm*comp[etype] per edge
        const unsigned short* __restrict__ Wb,    // [128 o][512 k] bf16
        const float* __restrict__ bias,
        void* __restrict__ outp, int M, int write_bf16) {
    __shared__ char lds[DT * 1024];               // 32 KB: AggTile[32][512] bf16
    const int tid  = threadIdx.x;
    const int wid  = tid >> 6;
    const int lane = tid & 63;
    const int v0   = blockIdx.x * DT;

    // ---------------- phase A: per-basis aggregation ----------------
#pragma unroll
    for (int i = 0; i < 4; ++i) {
        const int vl = wid * 4 + i;
        const int v  = v0 + vl;
        float a0x = 0.f, a0y = 0.f, a1x = 0.f, a1y = 0.f;
        float a2x = 0.f, a2y = 0.f, a3x = 0.f, a3y = 0.f;
        if (v < M) {
            const int beg = offs[v], end = offs[v + 1];
            for (int base = beg; base < end; base += 64) {
                const int cnt = min(64, end - base);
                int s = 0; float4 w = make_float4(0.f, 0.f, 0.f, 0.f);
                if (lane < cnt) { s = ridx[base + lane]; w = cw[base + lane]; }
                int j = 0;
                for (; j + 4 <= cnt; j += 4) {
                    int s0 = __shfl(s, j),     s1 = __shfl(s, j + 1);
                    int s2 = __shfl(s, j + 2), s3 = __shfl(s, j + 3);
                    unsigned u0 = *(const unsigned*)(hin + (size_t)s0 * H + lane * 2);
                    unsigned u1 = *(const unsigned*)(hin + (size_t)s1 * H + lane * 2);
                    unsigned u2 = *(const unsigned*)(hin + (size_t)s2 * H + lane * 2);
                    unsigned u3 = *(const unsigned*)(hin + (size_t)s3 * H + lane * 2);
#define ACC(U, J) { \
    float lo = bf_lo(U), hi = bf_hi(U); \
    float wx = __shfl(w.x, J), wy = __shfl(w.y, J); \
    float wz = __shfl(w.z, J), ww = __shfl(w.w, J); \
    a0x += wx * lo; a0y += wx * hi; a1x += wy * lo; a1y += wy * hi; \
    a2x += wz * lo; a2y += wz * hi; a3x += ww * lo; a3y += ww * hi; }
                    ACC(u0, j) ACC(u1, j + 1) ACC(u2, j + 2) ACC(u3, j + 3)
                }
                for (; j < cnt; ++j) {
                    int sj = __shfl(s, j);
                    unsigned u = *(const unsigned*)(hin + (size_t)sj * H + lane * 2);
                    ACC(u, j)
                }
#undef ACC
            }
        }
        // write AggTile row vl: 4 bases x packed 2 bf16 per lane (full 1024 B covered)
        char* row = lds + vl * 1024;
        const int swz = (vl & 7) << 4;
        *(unsigned*)(row + ((0 * 256 + lane * 4) ^ swz)) = (unsigned)f2bf(a0x) | ((unsigned)f2bf(a0y) << 16);
        *(unsigned*)(row + ((1 * 256 + lane * 4) ^ swz)) = (unsigned)f2bf(a1x) | ((unsigned)f2bf(a1y) << 16);
        *(unsigned*)(row + ((2 * 256 + lane * 4) ^ swz)) = (unsigned)f2bf(a2x) | ((unsigned)f2bf(a2y) << 16);
        *(unsigned*)(row + ((3 * 256 + lane * 4) ^ swz)) = (unsigned)f2bf(a3x) | ((unsigned)f2bf(a3y) << 16);
    }
    __syncthreads();

    // ---------------- phase B: [32 x 512] @ [512 x 128] ----------------
    const int n0 = wid * 16;           // this wave's 16 output cols
    const int lr = lane & 15;
    const int lg = lane >> 4;
    const char* bbase = (const char*)Wb + (size_t)(n0 + lr) * (NB * H) * 2;
    const int swz = (lr & 7) << 4;

    f32x4 acc0 = (f32x4){0.f, 0.f, 0.f, 0.f};
    f32x4 acc1 = (f32x4){0.f, 0.f, 0.f, 0.f};
#pragma unroll
    for (int ks = 0; ks < 16; ++ks) {
        const int kb = ks * 64 + lg * 16;
        short8 b  = *(const short8*)(bbase + kb);
        short8 a0 = *(const short8*)(lds + (lr)      * 1024 + (kb ^ swz));
        short8 a1 = *(const short8*)(lds + (16 + lr) * 1024 + (kb ^ swz));
        acc0 = __builtin_amdgcn_mfma_f32_16x16x32_bf16(a0, b, acc0, 0, 0, 0);
        acc1 = __builtin_amdgcn_mfma_f32_16x16x32_bf16(a1, b, acc1, 0, 0, 0);
    }

    const float bcol = bias[n0 + lr];
#pragma unroll
    for (int m = 0; m < 2; ++m) {
        const f32x4 a = m ? acc1 : acc0;
#pragma unroll
        for (int j = 0; j < 4; ++j) {
            const int rl   = m * 16 + lg * 4 + j;
            const int grow = v0 + rl;
            if (grow < M) {
                float val = fmaxf(a[j] + bcol, 0.f);
                if (write_bf16)
                    ((unsigned short*)outp)[(size_t)grow * H + n0 + lr] = f2bf(val);
                else
                    ((float*)outp)[(size_t)grow * H + n0 + lr] = val;
            }
        }
    }
}

extern "C" void kernel_launch(void* const* d_in, const int* in_sizes, int n_in,
                              void* d_out, int out_size, void* d_ws, size_t ws_size,
                              hipStream_t stream) {
    const float* feats  = (const float*)d_in[0];
    const int*   src    = (const int*)  d_in[1];
    const int*   dst    = (const int*)  d_in[2];
    const int*   etype  = (const int*)  d_in[3];
    const float* norm   = (const float*)d_in[4];
    const float* basis0 = (const float*)d_in[5];
    const float* comp0  = (const float*)d_in[6];
    const float* bias0  = (const float*)d_in[7];
    const float* basis1 = (const float*)d_in[8];
    const float* comp1  = (const float*)d_in[9];
    const float* bias1  = (const float*)d_in[10];
    float* out = (float*)d_out;

    const int M = in_sizes[0] / H;     // 50000
    const int E = in_sizes[1];         // 600000

    // workspace carve-up (256B aligned)
    char* ws = (char*)d_ws;
    size_t cur = 0;
    auto take = [&](size_t bytes) { void* p = ws + cur; cur += (bytes + 255) & ~(size_t)255; return p; };
    unsigned short* hbf  = (unsigned short*)take((size_t)M * H * 2);           // 12.8 MB
    unsigned short* h1bf = (unsigned short*)take((size_t)M * H * 2);           // 12.8 MB
    unsigned short* Wb   = (unsigned short*)take((size_t)2 * H * NB * H * 2);  // 256 KB
    int*    counts  = (int*)take((size_t)M * 4);
    int*    offs    = (int*)take((size_t)(M + 1) * 4);
    int*    partial = (int*)take((size_t)M * 4);
    int*    bsums   = (int*)take((size_t)64 * 4);
    int*    ridx    = (int*)take((size_t)E * 4);
    float4* cw      = (float4*)take((size_t)E * 16);                           // 9.6 MB

    dim3 blk(256);
    int mb  = (M + 255) / 256;
    int eb  = (E + 255) / 256;
    int n4  = M * H / 4;
    int cb  = (n4 + 255) / 256;
    int nsb = (M + 1023) / 1024;         // 49 <= 64
    int fb  = (M + DT - 1) / DT;         // 1563

    // ---- graph prep (stateless every call) ----
    zero_i       <<<mb, blk, 0, stream>>>(counts, M);
    hist_dst     <<<eb, blk, 0, stream>>>(dst, counts, E);
    scan_blocks  <<<nsb, 1024, 0, stream>>>(counts, partial, bsums, M);
    scan_carry   <<<1, 64, 0, stream>>>(bsums, nsb);
    scan_add     <<<mb, blk, 0, stream>>>(partial, bsums, offs, M);
    convert_bf16 <<<cb, blk, 0, stream>>>(feats, hbf, n4);
    make_wb      <<<dim3(NB, H, 2), 128, 0, stream>>>(basis0, basis1, Wb);

    // ---- layer 0 ----
    scatter_edges<<<eb, blk, 0, stream>>>(src, dst, etype, norm, comp0, offs, counts, ridx, cw, E);
    fused_layer  <<<fb, 512, 0, stream>>>(hbf, offs, ridx, cw, Wb, bias0, h1bf, M, 1);

    // ---- layer 1 (re-scatter with comp1 weights; counts consumed -> rebuild) ----
    zero_i       <<<mb, blk, 0, stream>>>(counts, M);
    hist_dst     <<<eb, blk, 0, stream>>>(dst, counts, E);
    scatter_edges<<<eb, blk, 0, stream>>>(src, dst, etype, norm, comp1, offs, counts, ridx, cw, E);
    fused_layer  <<<fb, 512, 0, stream>>>(h1bf, offs, ridx, cw, Wb + (size_t)H * NB * H, bias1, out, M, 0);
}

// Round 6
// 271.596 us; speedup vs baseline: 1.1382x; 1.1382x over previous
//
#include <hip/hip_runtime.h>

#define H    128
#define NB   4
#define NR   8
#define DT   32    // dst-nodes per block in fused kernel

typedef __attribute__((ext_vector_type(8))) short short8;
typedef __attribute__((ext_vector_type(4))) float f32x4;

static __device__ __forceinline__ unsigned short f2bf(float f) {
    unsigned u = __float_as_uint(f);
    unsigned r = (u + 0x7fffu + ((u >> 16) & 1u)) >> 16;
    return (unsigned short)r;
}
static __device__ __forceinline__ float bfe(short s) {
    return __uint_as_float(((unsigned)(unsigned short)s) << 16);
}

// ---------------- zero int array ----------------
__global__ __launch_bounds__(256) void zero_i(int* __restrict__ p, int n) {
    int i = blockIdx.x * 256 + threadIdx.x;
    if (i < n) p[i] = 0;
}

// ------- histogram + per-edge arrival rank -------
__global__ __launch_bounds__(256) void hist_rank(const int* __restrict__ dst,
                                                 int* __restrict__ counts,
                                                 int* __restrict__ rank, int E) {
    int e = blockIdx.x * 256 + threadIdx.x;
    if (e < E) rank[e] = atomicAdd(&counts[dst[e]], 1);
}

// ---------------- hierarchical scan stage 1 ----------------
__global__ __launch_bounds__(1024) void scan_blocks(const int* __restrict__ counts,
                                                    int* __restrict__ partial,
                                                    int* __restrict__ blocksums, int n) {
    __shared__ int buf[1024];
    int tid = threadIdx.x;
    int i = blockIdx.x * 1024 + tid;
    buf[tid] = (i < n) ? counts[i] : 0;
    __syncthreads();
#pragma unroll
    for (int off = 1; off < 1024; off <<= 1) {
        int t = (tid >= off) ? buf[tid - off] : 0;
        __syncthreads();
        buf[tid] += t;
        __syncthreads();
    }
    if (i < n) partial[i] = buf[tid];
    if (tid == 1023) blocksums[blockIdx.x] = buf[1023];
}

// ---------------- stage 2: single-wave scan of block sums (nb <= 64) ----------------
__global__ __launch_bounds__(64) void scan_carry(int* __restrict__ blocksums, int nb) {
    int tid = threadIdx.x;
    int v = (tid < nb) ? blocksums[tid] : 0;
#pragma unroll
    for (int off = 1; off < 64; off <<= 1) {
        int t = __shfl_up(v, off);
        if (tid >= off) v += t;
    }
    if (tid < nb) blocksums[tid] = v;
}

// ---------------- stage 3: add carry, emit offs[0..n] ----------------
__global__ __launch_bounds__(256) void scan_add(const int* __restrict__ partial,
                                                const int* __restrict__ blocksums,
                                                int* __restrict__ offs, int n) {
    int i = blockIdx.x * 256 + threadIdx.x;
    if (i >= n) return;
    int b = i >> 10;
    int carry = (b > 0) ? blocksums[b - 1] : 0;
    offs[i + 1] = partial[i] + carry;
    if (i == 0) offs[0] = 0;
}

// ------- scatter edges into CSR (atomic-free, rank-based); both layers' weights -------
__global__ __launch_bounds__(256) void scatter_edges(
        const int* __restrict__ src, const int* __restrict__ dst,
        const int* __restrict__ etype, const float* __restrict__ norm,
        const float* __restrict__ comp0, const float* __restrict__ comp1,
        const int* __restrict__ offs, const int* __restrict__ rank,
        int* __restrict__ ridx, float4* __restrict__ cw0, float4* __restrict__ cw1, int E) {
    int e = blockIdx.x * 256 + threadIdx.x;
    if (e >= E) return;
    int pos = offs[dst[e]] + rank[e];
    ridx[pos] = src[e];
    float w = norm[e];
    int et = etype[e];
    float4 c0 = *(const float4*)(comp0 + et * NB);
    float4 c1 = *(const float4*)(comp1 + et * NB);
    cw0[pos] = make_float4(w * c0.x, w * c0.y, w * c0.z, w * c0.w);
    cw1[pos] = make_float4(w * c1.x, w * c1.y, w * c1.z, w * c1.w);
}

// ---------------- f32 -> bf16 convert ----------------
__global__ __launch_bounds__(256) void convert_bf16(const float* __restrict__ in,
                                                    unsigned short* __restrict__ out, int n4) {
    int i = blockIdx.x * 256 + threadIdx.x;
    if (i >= n4) return;
    float4 v = ((const float4*)in)[i];
    ushort4 o;
    o.x = f2bf(v.x); o.y = f2bf(v.y); o.z = f2bf(v.z); o.w = f2bf(v.w);
    ((ushort4*)out)[i] = o;
}

// ---- Wb build: Wb[l][o][b*128+d] = bf16(basis_l[b][d][o])  (pure transpose) ----
__global__ __launch_bounds__(128) void make_wb(
        const float* __restrict__ basis0, const float* __restrict__ basis1,
        unsigned short* __restrict__ Wb) {
    int b = blockIdx.x;        // 0..3
    int d = blockIdx.y;        // 0..127
    int l = blockIdx.z;        // 0..1
    int o = threadIdx.x;       // 0..127
    const float* basis = l ? basis1 : basis0;
    float s = basis[((size_t)b * H + d) * H + o];
    Wb[((size_t)l * H + o) * (NB * H) + b * H + d] = f2bf(s);
}

// ---------------- fused layer: basis-agg (LDS) + MFMA GEMM + bias + relu ----------------
// block = 512 threads (8 waves), DT=32 dst nodes, K = NB*H = 512.
// Phase A: wave w aggregates nodes w*4..w*4+3. 4 lane-groups of 16 process 4 edges
//          per iteration (16B gather each), f32 accum, cross-group shfl reduce.
// Phase B: wave w computes output cols [w*16, w*16+16) for all 32 rows.
__global__ __launch_bounds__(512) void fused_layer(
        const unsigned short* __restrict__ hin,   // [M][128] bf16
        const int* __restrict__ offs,             // [M+1]
        const int* __restrict__ ridx,             // src per edge, CSR by dst
        const float4* __restrict__ cw,            // norm*comp[etype] per edge (this layer)
        const unsigned short* __restrict__ Wb,    // [128 o][512 k] bf16
        const float* __restrict__ bias,
        void* __restrict__ outp, int M, int write_bf16) {
    __shared__ char lds[DT * 1024];               // 32 KB: AggTile[32][512] bf16
    const int tid  = threadIdx.x;
    const int wid  = tid >> 6;
    const int lane = tid & 63;
    const int grp  = lane >> 4;    // edge slot within 4-edge batch
    const int gl   = lane & 15;    // 16B chunk within source row
    const int v0   = blockIdx.x * DT;

    // ---------------- phase A ----------------
#pragma unroll
    for (int i = 0; i < 4; ++i) {
        const int vl = wid * 4 + i;
        const int v  = v0 + vl;
        float A0[8], A1[8], A2[8], A3[8];
#pragma unroll
        for (int c = 0; c < 8; ++c) { A0[c] = 0.f; A1[c] = 0.f; A2[c] = 0.f; A3[c] = 0.f; }

        if (v < M) {
            const int beg = offs[v], end = offs[v + 1];
            for (int base = beg; base < end; base += 64) {
                const int cnt = min(64, end - base);
                int s = 0; float4 w = make_float4(0.f, 0.f, 0.f, 0.f);
                if (lane < cnt) { s = ridx[base + lane]; w = cw[base + lane]; }
                const int nj = (cnt + 3) >> 2;
                for (int j = 0; j < nj; ++j) {
                    const int el = j * 4 + grp;
                    int   sg = __shfl(s, el);
                    float wx = __shfl(w.x, el), wy = __shfl(w.y, el);
                    float wz = __shfl(w.z, el), ww = __shfl(w.w, el);
                    short8 hv = *(const short8*)(hin + (size_t)sg * H + gl * 8);
#pragma unroll
                    for (int c = 0; c < 8; ++c) {
                        float f = bfe(hv[c]);
                        A0[c] = fmaf(wx, f, A0[c]);
                        A1[c] = fmaf(wy, f, A1[c]);
                        A2[c] = fmaf(wz, f, A2[c]);
                        A3[c] = fmaf(ww, f, A3[c]);
                    }
                }
            }
        }
        // cross-group reduction (groups processed disjoint edge subsets)
#pragma unroll
        for (int c = 0; c < 8; ++c) {
            A0[c] += __shfl_xor(A0[c], 16); A0[c] += __shfl_xor(A0[c], 32);
            A1[c] += __shfl_xor(A1[c], 16); A1[c] += __shfl_xor(A1[c], 32);
            A2[c] += __shfl_xor(A2[c], 16); A2[c] += __shfl_xor(A2[c], 32);
            A3[c] += __shfl_xor(A3[c], 16); A3[c] += __shfl_xor(A3[c], 32);
        }
        // lane writes basis `grp`, cols [gl*8, gl*8+8) -> 16B, swizzled
        float S[8];
#pragma unroll
        for (int c = 0; c < 8; ++c)
            S[c] = (grp == 0) ? A0[c] : (grp == 1) ? A1[c] : (grp == 2) ? A2[c] : A3[c];
        uint4 pk;
        pk.x = (unsigned)f2bf(S[0]) | ((unsigned)f2bf(S[1]) << 16);
        pk.y = (unsigned)f2bf(S[2]) | ((unsigned)f2bf(S[3]) << 16);
        pk.z = (unsigned)f2bf(S[4]) | ((unsigned)f2bf(S[5]) << 16);
        pk.w = (unsigned)f2bf(S[6]) | ((unsigned)f2bf(S[7]) << 16);
        char* row = lds + vl * 1024;
        *(uint4*)(row + ((grp * 256 + gl * 16) ^ ((vl & 7) << 4))) = pk;
    }
    __syncthreads();

    // ---------------- phase B: [32 x 512] @ [512 x 128] ----------------
    const int n0 = wid * 16;           // this wave's 16 output cols
    const int lr = lane & 15;
    const int lg = lane >> 4;
    const char* bbase = (const char*)Wb + (size_t)(n0 + lr) * (NB * H) * 2;
    const int swz = (lr & 7) << 4;

    f32x4 acc0 = (f32x4){0.f, 0.f, 0.f, 0.f};
    f32x4 acc1 = (f32x4){0.f, 0.f, 0.f, 0.f};
#pragma unroll
    for (int ks = 0; ks < 16; ++ks) {
        const int kb = ks * 64 + lg * 16;
        short8 b  = *(const short8*)(bbase + kb);
        short8 a0 = *(const short8*)(lds + (lr)      * 1024 + (kb ^ swz));
        short8 a1 = *(const short8*)(lds + (16 + lr) * 1024 + (kb ^ swz));
        acc0 = __builtin_amdgcn_mfma_f32_16x16x32_bf16(a0, b, acc0, 0, 0, 0);
        acc1 = __builtin_amdgcn_mfma_f32_16x16x32_bf16(a1, b, acc1, 0, 0, 0);
    }

    const float bcol = bias[n0 + lr];
#pragma unroll
    for (int m = 0; m < 2; ++m) {
        const f32x4 a = m ? acc1 : acc0;
#pragma unroll
        for (int j = 0; j < 4; ++j) {
            const int rl   = m * 16 + lg * 4 + j;
            const int grow = v0 + rl;
            if (grow < M) {
                float val = fmaxf(a[j] + bcol, 0.f);
                if (write_bf16)
                    ((unsigned short*)outp)[(size_t)grow * H + n0 + lr] = f2bf(val);
                else
                    ((float*)outp)[(size_t)grow * H + n0 + lr] = val;
            }
        }
    }
}

extern "C" void kernel_launch(void* const* d_in, const int* in_sizes, int n_in,
                              void* d_out, int out_size, void* d_ws, size_t ws_size,
                              hipStream_t stream) {
    const float* feats  = (const float*)d_in[0];
    const int*   src    = (const int*)  d_in[1];
    const int*   dst    = (const int*)  d_in[2];
    const int*   etype  = (const int*)  d_in[3];
    const float* norm   = (const float*)d_in[4];
    const float* basis0 = (const float*)d_in[5];
    const float* comp0  = (const float*)d_in[6];
    const float* bias0  = (const float*)d_in[7];
    const float* basis1 = (const float*)d_in[8];
    const float* comp1  = (const float*)d_in[9];
    const float* bias1  = (const float*)d_in[10];
    float* out = (float*)d_out;

    const int M = in_sizes[0] / H;     // 50000
    const int E = in_sizes[1];         // 600000

    // workspace carve-up (256B aligned)
    char* ws = (char*)d_ws;
    size_t cur = 0;
    auto take = [&](size_t bytes) { void* p = ws + cur; cur += (bytes + 255) & ~(size_t)255; return p; };
    unsigned short* hbf  = (unsigned short*)take((size_t)M * H * 2);           // 12.8 MB
    unsigned short* h1bf = (unsigned short*)take((size_t)M * H * 2);           // 12.8 MB
    unsigned short* Wb   = (unsigned short*)take((size_t)2 * H * NB * H * 2);  // 256 KB
    int*    counts  = (int*)take((size_t)M * 4);
    int*    offs    = (int*)take((size_t)(M + 1) * 4);
    int*    partial = (int*)take((size_t)M * 4);
    int*    bsums   = (int*)take((size_t)64 * 4);
    int*    rank    = (int*)take((size_t)E * 4);
    int*    ridx    = (int*)take((size_t)E * 4);
    float4* cw0     = (float4*)take((size_t)E * 16);                           // 9.6 MB
    float4* cw1     = (float4*)take((size_t)E * 16);                           // 9.6 MB

    dim3 blk(256);
    int mb  = (M + 255) / 256;
    int eb  = (E + 255) / 256;
    int n4  = M * H / 4;
    int cb  = (n4 + 255) / 256;
    int nsb = (M + 1023) / 1024;         // 49 <= 64
    int fb  = (M + DT - 1) / DT;         // 1563

    // ---- graph prep (stateless every call, single CSR build) ----
    zero_i       <<<mb, blk, 0, stream>>>(counts, M);
    hist_rank    <<<eb, blk, 0, stream>>>(dst, counts, rank, E);
    scan_blocks  <<<nsb, 1024, 0, stream>>>(counts, partial, bsums, M);
    scan_carry   <<<1, 64, 0, stream>>>(bsums, nsb);
    scan_add     <<<mb, blk, 0, stream>>>(partial, bsums, offs, M);
    scatter_edges<<<eb, blk, 0, stream>>>(src, dst, etype, norm, comp0, comp1,
                                          offs, rank, ridx, cw0, cw1, E);
    convert_bf16 <<<cb, blk, 0, stream>>>(feats, hbf, n4);
    make_wb      <<<dim3(NB, H, 2), 128, 0, stream>>>(basis0, basis1, Wb);

    // ---- layer 0 ----
    fused_layer<<<fb, 512, 0, stream>>>(hbf, offs, ridx, cw0, Wb, bias0, h1bf, M, 1);
    // ---- layer 1 ----
    fused_layer<<<fb, 512, 0, stream>>>(h1bf, offs, ridx, cw1,
                                        Wb + (size_t)H * NB * H, bias1, out, M, 0);
}

// Round 7
// 191.572 us; speedup vs baseline: 1.6137x; 1.4177x over previous
//
#include <hip/hip_runtime.h>

#define H    128
#define NB   4
#define DT   32    // dst-nodes per block in fused kernel

typedef __attribute__((ext_vector_type(8))) short short8;
typedef __attribute__((ext_vector_type(4))) float f32x4;

static __device__ __forceinline__ unsigned short f2bf(float f) {
    unsigned u = __float_as_uint(f);
    unsigned r = (u + 0x7fffu + ((u >> 16) & 1u)) >> 16;
    return (unsigned short)r;
}
static __device__ __forceinline__ float bf_lo(unsigned v) {
    return __uint_as_float((v & 0xffffu) << 16);
}
static __device__ __forceinline__ float bf_hi(unsigned v) {
    return __uint_as_float(v & 0xffff0000u);
}
static __device__ __forceinline__ float bfe(short s) {
    return __uint_as_float(((unsigned)(unsigned short)s) << 16);
}

// ---------------- zero int array ----------------
__global__ __launch_bounds__(256) void zero_i(int* __restrict__ p, int n) {
    int i = blockIdx.x * 256 + threadIdx.x;
    if (i < n) p[i] = 0;
}

// ------- histogram + per-edge arrival rank -------
__global__ __launch_bounds__(256) void hist_rank(const int* __restrict__ dst,
                                                 int* __restrict__ counts,
                                                 int* __restrict__ rank, int E) {
    int e = blockIdx.x * 256 + threadIdx.x;
    if (e < E) rank[e] = atomicAdd(&counts[dst[e]], 1);
}

// ---------------- hierarchical scan stage 1 ----------------
__global__ __launch_bounds__(1024) void scan_blocks(const int* __restrict__ counts,
                                                    int* __restrict__ partial,
                                                    int* __restrict__ blocksums, int n) {
    __shared__ int buf[1024];
    int tid = threadIdx.x;
    int i = blockIdx.x * 1024 + tid;
    buf[tid] = (i < n) ? counts[i] : 0;
    __syncthreads();
#pragma unroll
    for (int off = 1; off < 1024; off <<= 1) {
        int t = (tid >= off) ? buf[tid - off] : 0;
        __syncthreads();
        buf[tid] += t;
        __syncthreads();
    }
    if (i < n) partial[i] = buf[tid];
    if (tid == 1023) blocksums[blockIdx.x] = buf[1023];
}

// ---------------- stage 2: single-wave scan of block sums (nb <= 64) ----------------
__global__ __launch_bounds__(64) void scan_carry(int* __restrict__ blocksums, int nb) {
    int tid = threadIdx.x;
    int v = (tid < nb) ? blocksums[tid] : 0;
#pragma unroll
    for (int off = 1; off < 64; off <<= 1) {
        int t = __shfl_up(v, off);
        if (tid >= off) v += t;
    }
    if (tid < nb) blocksums[tid] = v;
}

// ---------------- stage 3: add carry, emit offs[0..n] ----------------
__global__ __launch_bounds__(256) void scan_add(const int* __restrict__ partial,
                                                const int* __restrict__ blocksums,
                                                int* __restrict__ offs, int n) {
    int i = blockIdx.x * 256 + threadIdx.x;
    if (i >= n) return;
    int b = i >> 10;
    int carry = (b > 0) ? blocksums[b - 1] : 0;
    offs[i + 1] = partial[i] + carry;
    if (i == 0) offs[0] = 0;
}

// ------- scatter edges into CSR (rank-based); 16B edge records per layer -------
// rec = {src, w[0..1] packed bf16, w[2..3] packed bf16, 0} where w = norm*comp[etype]
__global__ __launch_bounds__(256) void scatter_edges(
        const int* __restrict__ src, const int* __restrict__ dst,
        const int* __restrict__ etype, const float* __restrict__ norm,
        const float* __restrict__ comp0, const float* __restrict__ comp1,
        const int* __restrict__ offs, const int* __restrict__ rank,
        uint4* __restrict__ er0, uint4* __restrict__ er1, int E) {
    int e = blockIdx.x * 256 + threadIdx.x;
    if (e >= E) return;
    int pos = offs[dst[e]] + rank[e];
    float w = norm[e];
    int et = etype[e];
    float4 c0 = *(const float4*)(comp0 + et * NB);
    float4 c1 = *(const float4*)(comp1 + et * NB);
    uint4 r0, r1;
    r0.x = (unsigned)src[e];
    r0.y = (unsigned)f2bf(w * c0.x) | ((unsigned)f2bf(w * c0.y) << 16);
    r0.z = (unsigned)f2bf(w * c0.z) | ((unsigned)f2bf(w * c0.w) << 16);
    r0.w = 0;
    r1.x = (unsigned)src[e];
    r1.y = (unsigned)f2bf(w * c1.x) | ((unsigned)f2bf(w * c1.y) << 16);
    r1.z = (unsigned)f2bf(w * c1.z) | ((unsigned)f2bf(w * c1.w) << 16);
    r1.w = 0;
    er0[pos] = r0;
    er1[pos] = r1;
}

// ---------------- f32 -> bf16 convert ----------------
__global__ __launch_bounds__(256) void convert_bf16(const float* __restrict__ in,
                                                    unsigned short* __restrict__ out, int n4) {
    int i = blockIdx.x * 256 + threadIdx.x;
    if (i >= n4) return;
    float4 v = ((const float4*)in)[i];
    ushort4 o;
    o.x = f2bf(v.x); o.y = f2bf(v.y); o.z = f2bf(v.z); o.w = f2bf(v.w);
    ((ushort4*)out)[i] = o;
}

// ---- Wb build: Wb[l][o][b*128+d] = bf16(basis_l[b][d][o])  (pure transpose) ----
__global__ __launch_bounds__(128) void make_wb(
        const float* __restrict__ basis0, const float* __restrict__ basis1,
        unsigned short* __restrict__ Wb) {
    int b = blockIdx.x;        // 0..3
    int d = blockIdx.y;        // 0..127
    int l = blockIdx.z;        // 0..1
    int o = threadIdx.x;       // 0..127
    const float* basis = l ? basis1 : basis0;
    float s = basis[((size_t)b * H + d) * H + o];
    Wb[((size_t)l * H + o) * (NB * H) + b * H + d] = f2bf(s);
}

// ---------------- fused layer: basis-agg (LDS) + MFMA GEMM + bias + relu ----------------
// block = 512 threads (8 waves), DT=32 dst nodes, K = NB*H = 512.
// Phase A: thread = (node nl = tid>>4, chunk ch = tid&15). Walks node's edge list
//          privately: 16B edge-rec + 16B row gather + 32 FMAs. No shfl, no x-lane.
// Phase B: wave w computes output cols [w*16, w*16+16) for all 32 rows.
#define EDGE_ACC(REC, HV) {                                             \
    float wa = bf_lo(REC.y), wb = bf_hi(REC.y);                         \
    float wc = bf_lo(REC.z), wd = bf_hi(REC.z);                         \
    _Pragma("unroll")                                                   \
    for (int c = 0; c < 8; ++c) {                                       \
        float f = bfe(HV[c]);                                           \
        a0[c] = fmaf(wa, f, a0[c]); a1[c] = fmaf(wb, f, a1[c]);         \
        a2[c] = fmaf(wc, f, a2[c]); a3[c] = fmaf(wd, f, a3[c]);         \
    } }

__global__ __launch_bounds__(512) void fused_layer(
        const unsigned short* __restrict__ hin,   // [M][128] bf16
        const int* __restrict__ offs,             // [M+1]
        const uint4* __restrict__ er,             // 16B edge records (this layer)
        const unsigned short* __restrict__ Wb,    // [128 o][512 k] bf16
        const float* __restrict__ bias,
        void* __restrict__ outp, int M, int write_bf16) {
    __shared__ char lds[DT * 1024];               // 32 KB: AggTile[32][512] bf16
    const int tid  = threadIdx.x;
    const int nl   = tid >> 4;     // local node 0..31
    const int ch   = tid & 15;     // 16B chunk of the 256B row
    const int v0   = blockIdx.x * DT;
    const int v    = v0 + nl;

    // ---------------- phase A: private per-thread aggregation ----------------
    float a0[8], a1[8], a2[8], a3[8];
#pragma unroll
    for (int c = 0; c < 8; ++c) { a0[c] = 0.f; a1[c] = 0.f; a2[c] = 0.f; a3[c] = 0.f; }

    if (v < M) {
        const int beg = offs[v], end = offs[v + 1];
        int e = beg;
        for (; e + 2 <= end; e += 2) {
            uint4 r0 = er[e];
            uint4 r1 = er[e + 1];
            short8 h0 = *(const short8*)(hin + (size_t)r0.x * H + ch * 8);
            short8 h1 = *(const short8*)(hin + (size_t)r1.x * H + ch * 8);
            EDGE_ACC(r0, h0)
            EDGE_ACC(r1, h1)
        }
        if (e < end) {
            uint4 r0 = er[e];
            short8 h0 = *(const short8*)(hin + (size_t)r0.x * H + ch * 8);
            EDGE_ACC(r0, h0)
        }
    }

    // write AggTile row nl: 4 bases x 16B, swizzled
    {
        char* row = lds + nl * 1024;
        const int swz = (nl & 7) << 4;
        uint4 pk;
#define PACK(A) pk.x = (unsigned)f2bf(A[0]) | ((unsigned)f2bf(A[1]) << 16); \
                pk.y = (unsigned)f2bf(A[2]) | ((unsigned)f2bf(A[3]) << 16); \
                pk.z = (unsigned)f2bf(A[4]) | ((unsigned)f2bf(A[5]) << 16); \
                pk.w = (unsigned)f2bf(A[6]) | ((unsigned)f2bf(A[7]) << 16);
        PACK(a0) *(uint4*)(row + ((0 * 256 + ch * 16) ^ swz)) = pk;
        PACK(a1) *(uint4*)(row + ((1 * 256 + ch * 16) ^ swz)) = pk;
        PACK(a2) *(uint4*)(row + ((2 * 256 + ch * 16) ^ swz)) = pk;
        PACK(a3) *(uint4*)(row + ((3 * 256 + ch * 16) ^ swz)) = pk;
#undef PACK
    }
    __syncthreads();

    // ---------------- phase B: [32 x 512] @ [512 x 128] ----------------
    const int wid  = tid >> 6;
    const int lane = tid & 63;
    const int n0 = wid * 16;           // this wave's 16 output cols
    const int lr = lane & 15;
    const int lg = lane >> 4;
    const char* bbase = (const char*)Wb + (size_t)(n0 + lr) * (NB * H) * 2;
    const int swz = (lr & 7) << 4;

    f32x4 acc0 = (f32x4){0.f, 0.f, 0.f, 0.f};
    f32x4 acc1 = (f32x4){0.f, 0.f, 0.f, 0.f};
#pragma unroll
    for (int ks = 0; ks < 16; ++ks) {
        const int kb = ks * 64 + lg * 16;
        short8 b  = *(const short8*)(bbase + kb);
        short8 av0 = *(const short8*)(lds + (lr)      * 1024 + (kb ^ swz));
        short8 av1 = *(const short8*)(lds + (16 + lr) * 1024 + (kb ^ swz));
        acc0 = __builtin_amdgcn_mfma_f32_16x16x32_bf16(av0, b, acc0, 0, 0, 0);
        acc1 = __builtin_amdgcn_mfma_f32_16x16x32_bf16(av1, b, acc1, 0, 0, 0);
    }

    const float bcol = bias[n0 + lr];
#pragma unroll
    for (int m = 0; m < 2; ++m) {
        const f32x4 a = m ? acc1 : acc0;
#pragma unroll
        for (int j = 0; j < 4; ++j) {
            const int rl   = m * 16 + lg * 4 + j;
            const int grow = v0 + rl;
            if (grow < M) {
                float val = fmaxf(a[j] + bcol, 0.f);
                if (write_bf16)
                    ((unsigned short*)outp)[(size_t)grow * H + n0 + lr] = f2bf(val);
                else
                    ((float*)outp)[(size_t)grow * H + n0 + lr] = val;
            }
        }
    }
}

extern "C" void kernel_launch(void* const* d_in, const int* in_sizes, int n_in,
                              void* d_out, int out_size, void* d_ws, size_t ws_size,
                              hipStream_t stream) {
    const float* feats  = (const float*)d_in[0];
    const int*   src    = (const int*)  d_in[1];
    const int*   dst    = (const int*)  d_in[2];
    const int*   etype  = (const int*)  d_in[3];
    const float* norm   = (const float*)d_in[4];
    const float* basis0 = (const float*)d_in[5];
    const float* comp0  = (const float*)d_in[6];
    const float* bias0  = (const float*)d_in[7];
    const float* basis1 = (const float*)d_in[8];
    const float* comp1  = (const float*)d_in[9];
    const float* bias1  = (const float*)d_in[10];
    float* out = (float*)d_out;

    const int M = in_sizes[0] / H;     // 50000
    const int E = in_sizes[1];         // 600000

    // workspace carve-up (256B aligned)
    char* ws = (char*)d_ws;
    size_t cur = 0;
    auto take = [&](size_t bytes) { void* p = ws + cur; cur += (bytes + 255) & ~(size_t)255; return p; };
    unsigned short* hbf  = (unsigned short*)take((size_t)M * H * 2);           // 12.8 MB
    unsigned short* h1bf = (unsigned short*)take((size_t)M * H * 2);           // 12.8 MB
    unsigned short* Wb   = (unsigned short*)take((size_t)2 * H * NB * H * 2);  // 256 KB
    int*   counts  = (int*)take((size_t)M * 4);
    int*   offs    = (int*)take((size_t)(M + 1) * 4);
    int*   partial = (int*)take((size_t)M * 4);
    int*   bsums   = (int*)take((size_t)64 * 4);
    int*   rank    = (int*)take((size_t)E * 4);
    uint4* er0     = (uint4*)take((size_t)E * 16);                             // 9.6 MB
    uint4* er1     = (uint4*)take((size_t)E * 16);                             // 9.6 MB

    dim3 blk(256);
    int mb  = (M + 255) / 256;
    int eb  = (E + 255) / 256;
    int n4  = M * H / 4;
    int cb  = (n4 + 255) / 256;
    int nsb = (M + 1023) / 1024;         // 49 <= 64
    int fb  = (M + DT - 1) / DT;         // 1563

    // ---- graph prep (stateless every call, single CSR build) ----
    zero_i       <<<mb, blk, 0, stream>>>(counts, M);
    hist_rank    <<<eb, blk, 0, stream>>>(dst, counts, rank, E);
    scan_blocks  <<<nsb, 1024, 0, stream>>>(counts, partial, bsums, M);
    scan_carry   <<<1, 64, 0, stream>>>(bsums, nsb);
    scan_add     <<<mb, blk, 0, stream>>>(partial, bsums, offs, M);
    scatter_edges<<<eb, blk, 0, stream>>>(src, dst, etype, norm, comp0, comp1,
                                          offs, rank, er0, er1, E);
    convert_bf16 <<<cb, blk, 0, stream>>>(feats, hbf, n4);
    make_wb      <<<dim3(NB, H, 2), 128, 0, stream>>>(basis0, basis1, Wb);

    // ---- layer 0 ----
    fused_layer<<<fb, 512, 0, stream>>>(hbf, offs, er0, Wb, bias0, h1bf, M, 1);
    // ---- layer 1 ----
    fused_layer<<<fb, 512, 0, stream>>>(h1bf, offs, er1,
                                        Wb + (size_t)H * NB * H, bias1, out, M, 0);
}